// Round 2
// baseline (1368.074 us; speedup 1.0000x reference)
//
#include <hip/hip_runtime.h>
#include <cstddef>

// VGG-16 fwd, batch=1. R4: persistent conv-chain mega-kernel.
//  - L2..L13 convs + all reduce/pool stages fused into ONE kernel (256 blocks,
//    1 block/CU via 120KB LDS) with device-scope grid barriers between stages
//  - conv body unchanged from R3: global_load_lds_dwordx4 staging, dbuf LDS,
//    counted vmcnt pipeline, raw s_barrier
//  - barrier: monotone arrival counter (memset per call), threadfence release/
//    acquire, AGENT-scope atomic spin (cross-XCD safe)
//  - dispatches 24 -> 7
//  - FC: fp32 GEMV, weight-BW-bound (~100us floor)

typedef __attribute__((ext_vector_type(8))) short short8;
typedef __attribute__((ext_vector_type(4))) float f32x4;

__device__ inline unsigned short f2bf(float f) {
    unsigned int u = __builtin_bit_cast(unsigned int, f);
    u += 0x7FFF + ((u >> 16) & 1);          // RNE
    return (unsigned short)(u >> 16);
}
__device__ inline float bf2f(unsigned short h) {
    unsigned int u = ((unsigned int)h) << 16;
    return __builtin_bit_cast(float, u);
}

// direct global->LDS 16B: LDS dest = M0 + lane*16 (wave-uniform base in m0)
__device__ __forceinline__ void gl_lds16(const void* src, unsigned m0v) {
    asm volatile("s_mov_b32 m0, %1\n\t"
                 "global_load_lds_dwordx4 %0, off"
                 :: "v"(src), "s"(m0v) : "memory");
}

// ---------------- fused weight transform: OIHW fp32 -> [pos][co][ci] bf16 ----
struct WtDesc { const float* src; unsigned dst; int cin; int cout; int blk0; };
struct WtArgs { WtDesc d[12]; };

__global__ __launch_bounds__(256)
void wt_all_k(WtArgs A, unsigned short* __restrict__ wt, unsigned short* __restrict__ guard)
{
    __shared__ unsigned short lds[4][9 * 520];     // per-wave [pos][ci], stride 520 pads banks
    const int tid = threadIdx.x, wv = tid >> 6, lane = tid & 63;
    if (blockIdx.x == 0 && tid < 128) guard[tid] = 0;

    int l = 0;
#pragma unroll
    for (int i = 1; i < 12; ++i) l = ((int)blockIdx.x >= A.d[i].blk0) ? i : l;
    const WtDesc D = A.d[l];
    const int co = ((int)blockIdx.x - D.blk0) * 4 + wv;
    const int n = D.cin * 9;
    const int cinP = D.cin + 8;

    // phase 1: coalesced float4 read of contiguous co-row, scatter to [pos][ci] in LDS
    const float4* src = (const float4*)(D.src + (size_t)co * n);
    for (int i = lane; i < (n >> 2); i += 64) {
        float4 v = src[i];
        unsigned short b[4] = {f2bf(v.x), f2bf(v.y), f2bf(v.z), f2bf(v.w)};
        const int f0 = i * 4;
#pragma unroll
        for (int k = 0; k < 4; ++k) {
            const int f = f0 + k, ci = f / 9, pos = f - ci * 9;
            lds[wv][pos * cinP + ci] = b[k];
        }
    }
    __syncthreads();
    // phase 2: coalesced bf16 writes, 8B per lane
    unsigned short* dstb = wt + D.dst;
#pragma unroll 1
    for (int pos = 0; pos < 9; ++pos) {
        unsigned short* drow = dstb + ((size_t)pos * D.cout + co) * D.cin;
        for (int c4 = lane; c4 < (D.cin >> 2); c4 += 64) {
            ushort4 u = *(const ushort4*)&lds[wv][pos * cinP + c4 * 4];
            *(ushort4*)(drow + c4 * 4) = u;
        }
    }
}

// ---------------- grid barrier (persistent kernel, 1 block/CU, grid=256) ----
__device__ __forceinline__ void gridbar(unsigned* cnt, unsigned& gen)
{
    __syncthreads();                       // drains each wave's vmem (HIP semantics)
    if (threadIdx.x == 0) {
        gen += 256;
        __threadfence();                   // release: wb L2 to device scope
        __hip_atomic_fetch_add(cnt, 1u, __ATOMIC_RELAXED, __HIP_MEMORY_SCOPE_AGENT);
        while (__hip_atomic_load(cnt, __ATOMIC_RELAXED, __HIP_MEMORY_SCOPE_AGENT) < gen)
            __builtin_amdgcn_s_sleep(8);
        __threadfence();                   // acquire: inv L1/L2
    }
    __syncthreads();
}

// ---------------- conv stage (persistent-kernel body) ----------------
// MODE: 0 relu+bf16 NHWC | 2 fp32 partial (ci-split) | 3 fused 2x2 maxpool+relu+bf16
template<int PR, int MODE>
__device__ __forceinline__ void conv_stage(
    unsigned short* wLdsA, unsigned short* iLdsA,
    const unsigned short* __restrict__ act,
    const unsigned short* __restrict__ wt,
    const unsigned short* __restrict__ guard,
    void* __restrict__ outp,
    int Cin, int Cout, int H, int W, int chunkCi,
    int vx, int vy, int vz, int tid)
{
    constexpr int NT = PR / 4;
    constexpr int ICELLS = (PR + 2) * 18;
    constexpr int ITIN = (ICELLS * 4 + 255) / 256;     // input gl_lds16 per thread
    constexpr int VL = 9 + ITIN;                       // loads per STAGE per thread
    static_assert(VL == 12 || VL == 15, "unexpected stage depth");

    const int lane = tid & 63, wv = tid >> 6;
    const int half = lane >> 4, l15 = lane & 15;
    const int tilesX = W >> 4;
    const int pY = vx / tilesX, pX = vx - pY * tilesX;
    const int y0 = pY * PR, x0 = pX * 16;
    const int cob = vy, s = vz;
    const int ciBeg = s * chunkCi;
    const int nCh = chunkCi >> 5;

    f32x4 acc[4][NT];
#pragma unroll
    for (int mt = 0; mt < 4; ++mt)
#pragma unroll
        for (int nt = 0; nt < NT; ++nt) acc[mt][nt] = (f32x4){0.f, 0.f, 0.f, 0.f};

    auto STAGE = [&](int buf, int ci0) {
        const unsigned wB = (unsigned)(size_t)(wLdsA + buf * 18432);
        const unsigned iB = (unsigned)(size_t)(iLdsA + buf * (ITIN * 2048));
        // weights: 9 pos x 64 co x 32 ci  (dest = linear idx*16)
#pragma unroll
        for (int it = 0; it < 9; ++it) {
            const int idx = it * 256 + tid;
            const int cell = idx >> 2, q = idx & 3;
            const int pos = cell >> 6, co = cell & 63;
            const unsigned short* src = wt +
                (size_t)(pos * Cout + (cob << 6) + co) * Cin + ci0 + q * 8;
            gl_lds16(src, __builtin_amdgcn_readfirstlane(wB + (unsigned)(it * 4096 + wv * 1024)));
        }
        // input halo tile: (PR+2) x 18 x 32ci, OOB lanes -> zero guard
#pragma unroll
        for (int it = 0; it < ITIN; ++it) {
            const int idx = it * 256 + tid;
            const int cell = idx >> 2, q = idx & 3;
            const int r = cell / 18, c = cell - r * 18;
            const int y = y0 - 1 + r, x = x0 - 1 + c;
            const bool ok = (idx < ICELLS * 4) & (y >= 0) & (y < H) & (x >= 0) & (x < W);
            const unsigned short* src = ok ?
                act + (size_t)(y * W + x) * Cin + ci0 + q * 8 : guard;
            gl_lds16(src, __builtin_amdgcn_readfirstlane(iB + (unsigned)(it * 4096 + wv * 1024)));
        }
    };

    STAGE(0, ciBeg);
    for (int t = 0; t < nCh; ++t) {
        const int buf = t & 1;
        if (t + 1 < nCh) {
            STAGE(buf ^ 1, ciBeg + ((t + 1) << 5));      // prefetch next chunk
            if constexpr (VL == 12) asm volatile("s_waitcnt vmcnt(12)" ::: "memory");
            else                    asm volatile("s_waitcnt vmcnt(15)" ::: "memory");
        } else {
            asm volatile("s_waitcnt vmcnt(0)" ::: "memory");
        }
        __builtin_amdgcn_s_barrier();
        asm volatile("" ::: "memory");

        const unsigned short* wP = wLdsA + buf * 18432;
        const unsigned short* iP = iLdsA + buf * (ITIN * 2048);
#pragma unroll
        for (int ky = 0; ky < 3; ++ky)
#pragma unroll
        for (int kx = 0; kx < 3; ++kx) {
            const int pos = ky * 3 + kx;
            short8 a[4];
#pragma unroll
            for (int mt = 0; mt < 4; ++mt)
                a[mt] = *(const short8*)&wP[((pos << 6) + (mt << 4) + l15) * 32 + half * 8];
#pragma unroll
            for (int nt = 0; nt < NT; ++nt) {
                const short8 b = *(const short8*)
                    &iP[((wv * NT + nt + ky) * 18 + l15 + kx) * 32 + half * 8];
#pragma unroll
                for (int mt = 0; mt < 4; ++mt)
                    acc[mt][nt] = __builtin_amdgcn_mfma_f32_16x16x32_bf16(a[mt], b, acc[mt][nt], 0, 0, 0);
            }
        }
        asm volatile("" ::: "memory");
        __builtin_amdgcn_s_barrier();
    }

    // ---- epilogue: D layout col(lane&15)=pixel-x, row((lane>>4)*4+reg)=co ----
    const int xg = x0 + l15;
    if (MODE == 3) {
        const int Wo = W >> 1;
#pragma unroll
        for (int mt = 0; mt < 4; ++mt)
#pragma unroll
        for (int nt = 0; nt < NT; nt += 2) {
            f32x4 a;
#pragma unroll
            for (int j = 0; j < 4; ++j) a[j] = fmaxf(acc[mt][nt][j], acc[mt][nt + 1][j]);
            f32x4 m;
#pragma unroll
            for (int j = 0; j < 4; ++j) m[j] = fmaxf(a[j], __shfl_xor(a[j], 1, 64));
            if ((l15 & 1) == 0) {
                const int yo = (y0 + wv * NT + nt) >> 1;
                const int xo = xg >> 1;
                const int co = (cob << 6) + (mt << 4) + half * 4;
                ushort4 u;
                u.x = f2bf(fmaxf(m[0], 0.f));
                u.y = f2bf(fmaxf(m[1], 0.f));
                u.z = f2bf(fmaxf(m[2], 0.f));
                u.w = f2bf(fmaxf(m[3], 0.f));
                *(ushort4*)((unsigned short*)outp + ((size_t)(yo * Wo + xo) * Cout + co)) = u;
            }
        }
    } else {
#pragma unroll
        for (int mt = 0; mt < 4; ++mt)
#pragma unroll
        for (int nt = 0; nt < NT; ++nt) {
            const int yg = y0 + wv * NT + nt;
            const int co = (cob << 6) + (mt << 4) + half * 4;
            const size_t base = (size_t)(yg * W + xg) * Cout + co;
            if (MODE == 2) {
                float4 v = make_float4(acc[mt][nt][0], acc[mt][nt][1], acc[mt][nt][2], acc[mt][nt][3]);
                *(float4*)((float*)outp + (size_t)s * Cout * H * W + base) = v;
            } else {
                ushort4 u;
                u.x = f2bf(fmaxf(acc[mt][nt][0], 0.f));
                u.y = f2bf(fmaxf(acc[mt][nt][1], 0.f));
                u.z = f2bf(fmaxf(acc[mt][nt][2], 0.f));
                u.w = f2bf(fmaxf(acc[mt][nt][3], 0.f));
                *(ushort4*)((unsigned short*)outp + base) = u;
            }
        }
    }
}

// ---------------- reduce/pool stages (grid-stride, persistent) ----------------
__device__ __forceinline__ void st_reduce_cvt(const float* __restrict__ P,
                                              unsigned short* __restrict__ out,
                                              int n4, int S, int bid, int tid)
{
    const float4* p4 = (const float4*)P;
    for (int i = bid * 256 + tid; i < n4; i += 65536) {
        float4 a = p4[i];
        for (int s = 1; s < S; ++s) {
            float4 b = p4[(size_t)i + (size_t)s * n4];
            a.x += b.x; a.y += b.y; a.z += b.z; a.w += b.w;
        }
        ushort4 u;
        u.x = f2bf(fmaxf(a.x, 0.f)); u.y = f2bf(fmaxf(a.y, 0.f));
        u.z = f2bf(fmaxf(a.z, 0.f)); u.w = f2bf(fmaxf(a.w, 0.f));
        *(ushort4*)(out + (size_t)i * 4) = u;
    }
}

__device__ __forceinline__ void st_reduce_pool_cvt(const float* __restrict__ P,
                                                   unsigned short* __restrict__ out,
                                                   int C, int H, int W, int S,
                                                   int bid, int tid)
{
    const int C4 = C >> 2, Wo = W >> 1, Ho = H >> 1;
    const int n = Ho * Wo * C4;
    const size_t CHW = (size_t)C * H * W;
    for (int i = bid * 256 + tid; i < n; i += 65536) {
        const int c4 = i % C4, p = i / C4;
        const int yo = p / Wo, xo = p - yo * Wo;
        const size_t b = (size_t)(2 * yo * W + 2 * xo) * C + c4 * 4;
        float4 v[4] = {{0,0,0,0},{0,0,0,0},{0,0,0,0},{0,0,0,0}};
        for (int s = 0; s < S; ++s) {
            const float* ps = P + s * CHW;
            float4 t0 = *(const float4*)(ps + b);
            float4 t1 = *(const float4*)(ps + b + C);
            float4 t2 = *(const float4*)(ps + b + (size_t)W * C);
            float4 t3 = *(const float4*)(ps + b + (size_t)W * C + C);
            v[0].x += t0.x; v[0].y += t0.y; v[0].z += t0.z; v[0].w += t0.w;
            v[1].x += t1.x; v[1].y += t1.y; v[1].z += t1.z; v[1].w += t1.w;
            v[2].x += t2.x; v[2].y += t2.y; v[2].z += t2.z; v[2].w += t2.w;
            v[3].x += t3.x; v[3].y += t3.y; v[3].z += t3.z; v[3].w += t3.w;
        }
        ushort4 u;
        u.x = f2bf(fmaxf(fmaxf(fmaxf(v[0].x, v[1].x), fmaxf(v[2].x, v[3].x)), 0.f));
        u.y = f2bf(fmaxf(fmaxf(fmaxf(v[0].y, v[1].y), fmaxf(v[2].y, v[3].y)), 0.f));
        u.z = f2bf(fmaxf(fmaxf(fmaxf(v[0].z, v[1].z), fmaxf(v[2].z, v[3].z)), 0.f));
        u.w = f2bf(fmaxf(fmaxf(fmaxf(v[0].w, v[1].w), fmaxf(v[2].w, v[3].w)), 0.f));
        *(ushort4*)(out + (size_t)p * C + c4 * 4) = u;
    }
}

__device__ __forceinline__ void st_reduce_pool_f32(const float* __restrict__ P,
                                                   float* __restrict__ out,
                                                   int C, int H, int W, int S,
                                                   int bid, int tid)
{
    const int Wo = W >> 1, Ho = H >> 1;
    const int n = Ho * Wo * C;
    const size_t CHW = (size_t)C * H * W;
    for (int i = bid * 256 + tid; i < n; i += 65536) {
        const int c = i % C, p = i / C;
        const int yo = p / Wo, xo = p - yo * Wo;
        float v0 = 0.f, v1 = 0.f, v2 = 0.f, v3 = 0.f;
        const size_t b = (size_t)(2 * yo * W + 2 * xo) * C + c;
        for (int s = 0; s < S; ++s) {
            const float* ps = P + s * CHW;
            v0 += ps[b]; v1 += ps[b + C]; v2 += ps[b + (size_t)W * C]; v3 += ps[b + (size_t)W * C + C];
        }
        out[(size_t)c * (Ho * Wo) + p] = fmaxf(fmaxf(fmaxf(v0, v1), fmaxf(v2, v3)), 0.f);
    }
}

// ---------------- mega kernel: L2..L13 + reduces, grid barriers ----------------
struct MegaArgs {
    const unsigned short* WT;
    const unsigned short* guard;
    unsigned short* bA;
    unsigned short* bB;
    float* Pf;
    float* fcIn;
    unsigned* cnt;
    unsigned wOff[12];
};

__global__ __launch_bounds__(256, 1)
void mega_k(MegaArgs A)
{
    __shared__ __align__(16) unsigned short wLds[2 * 18432];        // 72 KB
    __shared__ __align__(16) unsigned short iLds[2 * 6 * 2048];     // 48 KB (PR=16 worst case)
    const int bid = blockIdx.x, tid = threadIdx.x;
    unsigned gen = 0;
    unsigned* cnt = A.cnt;

    // L2: 64->64 @256^2, fused pool -> bB @128^2      grid (256,1,1)
    conv_stage<16, 3>(wLds, iLds, A.bA, A.WT + A.wOff[0], A.guard, A.bB,
                      64, 64, 256, 256, 64, bid, 0, 0, tid);
    gridbar(cnt, gen);
    // L3: 64->128 @128^2 -> bA                        grid (128,2,1)
    conv_stage<8, 0>(wLds, iLds, A.bB, A.WT + A.wOff[1], A.guard, A.bA,
                     64, 128, 128, 128, 64, bid & 127, bid >> 7, 0, tid);
    gridbar(cnt, gen);
    // L4: 128->128 @128^2, fused pool -> bB @64^2
    conv_stage<8, 3>(wLds, iLds, A.bA, A.WT + A.wOff[2], A.guard, A.bB,
                     128, 128, 128, 128, 128, bid & 127, bid >> 7, 0, tid);
    gridbar(cnt, gen);
    // L5: 128->256 @64^2, S=2                         grid (32,4,2)
    conv_stage<8, 2>(wLds, iLds, A.bB, A.WT + A.wOff[3], A.guard, A.Pf,
                     128, 256, 64, 64, 64, bid & 31, (bid >> 5) & 3, bid >> 7, tid);
    gridbar(cnt, gen);
    st_reduce_cvt(A.Pf, A.bA, 262144, 2, bid, tid);
    gridbar(cnt, gen);
    // L6: 256->256 @64^2, S=2
    conv_stage<8, 2>(wLds, iLds, A.bA, A.WT + A.wOff[4], A.guard, A.Pf,
                     256, 256, 64, 64, 128, bid & 31, (bid >> 5) & 3, bid >> 7, tid);
    gridbar(cnt, gen);
    st_reduce_cvt(A.Pf, A.bB, 262144, 2, bid, tid);
    gridbar(cnt, gen);
    // L7: 256->256 @64^2, S=2, pool -> bA @32^2
    conv_stage<8, 2>(wLds, iLds, A.bB, A.WT + A.wOff[5], A.guard, A.Pf,
                     256, 256, 64, 64, 128, bid & 31, (bid >> 5) & 3, bid >> 7, tid);
    gridbar(cnt, gen);
    st_reduce_pool_cvt(A.Pf, A.bA, 256, 64, 64, 2, bid, tid);
    gridbar(cnt, gen);
    // L8: 256->512 @32^2, S=4                         grid (8,8,4)
    conv_stage<8, 2>(wLds, iLds, A.bA, A.WT + A.wOff[6], A.guard, A.Pf,
                     256, 512, 32, 32, 64, bid & 7, (bid >> 3) & 7, bid >> 6, tid);
    gridbar(cnt, gen);
    st_reduce_cvt(A.Pf, A.bB, 131072, 4, bid, tid);
    gridbar(cnt, gen);
    // L9: 512->512 @32^2, S=4
    conv_stage<8, 2>(wLds, iLds, A.bB, A.WT + A.wOff[7], A.guard, A.Pf,
                     512, 512, 32, 32, 128, bid & 7, (bid >> 3) & 7, bid >> 6, tid);
    gridbar(cnt, gen);
    st_reduce_cvt(A.Pf, A.bA, 131072, 4, bid, tid);
    gridbar(cnt, gen);
    // L10: 512->512 @32^2, S=4, pool -> bB @16^2
    conv_stage<8, 2>(wLds, iLds, A.bA, A.WT + A.wOff[8], A.guard, A.Pf,
                     512, 512, 32, 32, 128, bid & 7, (bid >> 3) & 7, bid >> 6, tid);
    gridbar(cnt, gen);
    st_reduce_pool_cvt(A.Pf, A.bB, 512, 32, 32, 4, bid, tid);
    gridbar(cnt, gen);
    // L11: 512->512 @16^2, S=16                       grid (2,8,16)
    conv_stage<8, 2>(wLds, iLds, A.bB, A.WT + A.wOff[9], A.guard, A.Pf,
                     512, 512, 16, 16, 32, bid & 1, (bid >> 1) & 7, bid >> 4, tid);
    gridbar(cnt, gen);
    st_reduce_cvt(A.Pf, A.bA, 32768, 16, bid, tid);
    gridbar(cnt, gen);
    // L12
    conv_stage<8, 2>(wLds, iLds, A.bA, A.WT + A.wOff[10], A.guard, A.Pf,
                     512, 512, 16, 16, 32, bid & 1, (bid >> 1) & 7, bid >> 4, tid);
    gridbar(cnt, gen);
    st_reduce_cvt(A.Pf, A.bB, 32768, 16, bid, tid);
    gridbar(cnt, gen);
    // L13: S=16, pool -> fp32 NCHW flatten [512][8][8]
    conv_stage<8, 2>(wLds, iLds, A.bB, A.WT + A.wOff[11], A.guard, A.Pf,
                     512, 512, 16, 16, 32, bid & 1, (bid >> 1) & 7, bid >> 4, tid);
    gridbar(cnt, gen);
    st_reduce_pool_f32(A.Pf, A.fcIn, 512, 16, 16, 16, bid, tid);
}

// ---------------- L1: fp32 vector conv (Cin=3), epilogue -> NHWC bf16+relu ----
#define TILE 16
#define COB  32
__global__ __launch_bounds__(256)
void conv1_k(const float* __restrict__ in, const float* __restrict__ wt,
             unsigned short* __restrict__ out)
{
    const int Cin = 3, H = 256, W = 256, HW = H * W;
    __shared__ float sIn[2][648];
    __shared__ float sWt[2][768];

    const int tid = threadIdx.x;
    const int bx = blockIdx.x, by = blockIdx.y, co_blk = blockIdx.z;
    const int co_grp = tid >> 6;
    const int lane = tid & 63;
    const int tx = lane & 7, ty = lane >> 3;
    const int x0 = bx * TILE, y0 = by * TILE;

    int iLdsI[3], iG[3], iSub[3]; bool iOk[3];
    int wLdsI[3], wG[3], wSub[3]; bool wOk[3];
#pragma unroll
    for (int j = 0; j < 3; ++j) {
        int i = tid + j * 256;
        iOk[j] = false; iLdsI[j] = 0; iG[j] = 0; iSub[j] = 0;
        if (i < 648) {
            int sub = i / 324; int r = i - sub * 324;
            int iy = r / 18;   int ix = r - iy * 18;
            iSub[j] = sub; iLdsI[j] = sub * 324 + r;
            int y = y0 - 1 + iy, x = x0 - 1 + ix;
            if (y >= 0 && y < H && x >= 0 && x < W) { iOk[j] = true; iG[j] = sub * HW + y * W + x; }
        }
        wOk[j] = false; wLdsI[j] = 0; wG[j] = 0; wSub[j] = 0;
        if (i < 576) {
            int sub = i / 288; int r = i - sub * 288;
            int col = r / 9;   int k = r - col * 9;
            wSub[j] = sub; wLdsI[j] = sub * 384 + col * 12 + k;
            wG[j] = ((co_blk * COB + col) * Cin + sub) * 9 + k;
            wOk[j] = true;
        }
    }

    float4 acc[8];
#pragma unroll
    for (int c = 0; c < 8; ++c) acc[c] = make_float4(0.f, 0.f, 0.f, 0.f);

    const int nSteps = 2;   // ci pairs (0,1),(2,-)
    float rIn[3], rWt[3];
    {
#pragma unroll
        for (int j = 0; j < 3; ++j)
            rIn[j] = (iOk[j] && iSub[j] < 3) ? in[iG[j]] : 0.f;
#pragma unroll
        for (int j = 0; j < 3; ++j)
            rWt[j] = (wOk[j] && wSub[j] < 3) ? wt[wG[j]] : 0.f;
#pragma unroll
        for (int j = 0; j < 3; ++j) { if (tid + j * 256 < 648) sIn[0][iLdsI[j]] = rIn[j]; }
#pragma unroll
        for (int j = 0; j < 3; ++j) { if (tid + j * 256 < 576) sWt[0][wLdsI[j]] = rWt[j]; }
    }

    for (int t = 0; t < nSteps; ++t) {
        __syncthreads();
        const bool more = (t + 1) < nSteps;
        if (more) {
            const int ci0 = 2;
#pragma unroll
            for (int j = 0; j < 3; ++j)
                rIn[j] = (iOk[j] && (ci0 + iSub[j]) < 3) ? in[(size_t)ci0 * HW + iG[j]] : 0.f;
#pragma unroll
            for (int j = 0; j < 3; ++j)
                rWt[j] = (wOk[j] && (ci0 + wSub[j]) < 3) ? wt[(size_t)ci0 * 9 + wG[j]] : 0.f;
        }
        const int buf = t & 1;
        const float* sI = sIn[buf];
        const float* sW = sWt[buf];
#pragma unroll
        for (int sub = 0; sub < 2; ++sub) {
            float wv[4][4];
            const float* sp = sI + sub * 324 + (2 * ty) * 18 + 2 * tx;
#pragma unroll
            for (int r = 0; r < 4; ++r) {
                float2 a = *(const float2*)(sp + r * 18);
                float2 b = *(const float2*)(sp + r * 18 + 2);
                wv[r][0] = a.x; wv[r][1] = a.y; wv[r][2] = b.x; wv[r][3] = b.y;
            }
#pragma unroll
            for (int c = 0; c < 8; ++c) {
                const float* wp = sW + sub * 384 + (co_grp * 8 + c) * 12;
                float4 w0 = *(const float4*)wp;
                float4 w1 = *(const float4*)(wp + 4);
                float  w8 = wp[8];
                const float wk[9] = {w0.x, w0.y, w0.z, w0.w, w1.x, w1.y, w1.z, w1.w, w8};
                float* ac = (float*)&acc[c];
#pragma unroll
                for (int py = 0; py < 2; ++py)
#pragma unroll
                for (int px = 0; px < 2; ++px) {
                    float sacc = ac[py * 2 + px];
#pragma unroll
                    for (int kk = 0; kk < 9; ++kk)
                        sacc = fmaf(wv[py + kk / 3][px + kk % 3], wk[kk], sacc);
                    ac[py * 2 + px] = sacc;
                }
            }
        }
        if (more) {
#pragma unroll
            for (int j = 0; j < 3; ++j) { if (tid + j * 256 < 648) sIn[buf ^ 1][iLdsI[j]] = rIn[j]; }
#pragma unroll
            for (int j = 0; j < 3; ++j) { if (tid + j * 256 < 576) sWt[buf ^ 1][wLdsI[j]] = rWt[j]; }
        }
    }

    const int co0 = co_blk * COB + co_grp * 8;   // 8 consecutive co
#pragma unroll
    for (int py = 0; py < 2; ++py)
#pragma unroll
    for (int px = 0; px < 2; ++px) {
        const int y = y0 + 2 * ty + py, x = x0 + 2 * tx + px;
        unsigned short u8[8];
#pragma unroll
        for (int c = 0; c < 8; ++c)
            u8[c] = f2bf(fmaxf(((const float*)&acc[c])[py * 2 + px], 0.f));
        *(uint4*)(out + (size_t)(y * W + x) * 64 + co0) = *(uint4*)u8;
    }
}

// ---------------- FC GEMV (fp32, weight-BW-bound) ----------------
__global__ __launch_bounds__(256)
void gemv_k(const float* __restrict__ Wm, const float* __restrict__ xv,
            float* __restrict__ y, int K)
{
    __shared__ float red[4];
    const int tid = threadIdx.x;
    const float4* row = (const float4*)(Wm + (size_t)blockIdx.x * K);
    const float4* x4  = (const float4*)xv;
    const int K4 = K >> 2;
    float sum = 0.f;
    for (int i = tid; i < K4; i += 256) {
        float4 a = row[i], b = x4[i];
        sum += a.x * b.x + a.y * b.y + a.z * b.z + a.w * b.w;
    }
#pragma unroll
    for (int off = 32; off > 0; off >>= 1) sum += __shfl_down(sum, off, 64);
    if ((tid & 63) == 0) red[tid >> 6] = sum;
    __syncthreads();
    if (tid == 0) y[blockIdx.x] = red[0] + red[1] + red[2] + red[3];
}

// ---------------- launcher ----------------
extern "C" void kernel_launch(void* const* d_in, const int* in_sizes, int n_in,
                              void* d_out, int out_size, void* d_ws, size_t ws_size,
                              hipStream_t stream)
{
    (void)in_sizes; (void)n_in; (void)out_size; (void)ws_size;
    const float* x = (const float*)d_in[0];
    const float* cw[13];
    for (int i = 0; i < 13; ++i) cw[i] = (const float*)d_in[5 + i];
    const float* fw1 = (const float*)d_in[18];
    const float* fw2 = (const float*)d_in[19];
    const float* fw3 = (const float*)d_in[20];
    float* outp = (float*)d_out;

    // layers 2..13 (index 0..11 here)
    static const int CIN[12]  = {64, 64, 128, 128, 256, 256, 256, 512, 512, 512, 512, 512};
    static const int COUT[12] = {64, 128, 128, 256, 256, 256, 512, 512, 512, 512, 512, 512};

    char* ws = (char*)d_ws;
    size_t wOff[12]; size_t o = 0;
    for (int i = 0; i < 12; ++i) { wOff[i] = o; o += (size_t)9 * COUT[i] * CIN[i]; }
    unsigned short* WT = (unsigned short*)ws;               // 29.4 MB bf16
    unsigned short* guardp = WT + o;                        // 256 B zero guard
    size_t ao = ((o + 128) * 2 + 255) & ~(size_t)255;
    unsigned short* bA = (unsigned short*)(ws + ao);        // 8.39 MB
    unsigned short* bB = (unsigned short*)(ws + ao + 8388608);
    char* Pr = ws + ao + 2 * 8388608;                       // 8.39 MB partials
    float* Pf = (float*)Pr;
    unsigned* cnt = (unsigned*)(Pr + 8388608);              // grid-barrier counter
    float* fcIn = (float*)bA;                               // L13 result (128 KB)
    float* F1 = (float*)bB;
    float* F2 = F1 + 4096;

    // zero the grid-barrier counter (workspace is poisoned between calls)
    hipMemsetAsync(cnt, 0, 256, stream);

    // fused weight transform (also zeroes the halo guard)
    WtArgs wa; int blk = 0;
    {
        size_t oo = 0;
        for (int i = 0; i < 12; ++i) {
            wa.d[i].src = cw[i + 1];
            wa.d[i].dst = (unsigned)oo;
            wa.d[i].cin = CIN[i];
            wa.d[i].cout = COUT[i];
            wa.d[i].blk0 = blk;
            oo += (size_t)9 * COUT[i] * CIN[i];
            blk += COUT[i] / 4;
        }
    }
    wt_all_k<<<blk, 256, 0, stream>>>(wa, WT, guardp);

    // L1: fp32 vector conv 3->64 @256^2, out NHWC bf16
    conv1_k<<<dim3(16, 16, 2), 256, 0, stream>>>(x, cw[0], bA);

    // L2..L13 + reduces: one persistent kernel, 256 blocks (1/CU), grid barriers
    MegaArgs ma;
    ma.WT = WT; ma.guard = guardp; ma.bA = bA; ma.bB = bB;
    ma.Pf = Pf; ma.fcIn = fcIn; ma.cnt = cnt;
    for (int i = 0; i < 12; ++i) ma.wOff[i] = (unsigned)wOff[i];
    mega_k<<<256, 256, 0, stream>>>(ma);

    // FC head (fp32, HBM-bound on weights)
    gemv_k<<<4096, 256, 0, stream>>>(fw1, fcIn, F1, 32768);
    gemv_k<<<4096, 256, 0, stream>>>(fw2, F1, F2, 4096);
    gemv_k<<<1000, 256, 0, stream>>>(fw3, F2, outp, 4096);
}

// Round 3
// 968.746 us; speedup vs baseline: 1.4122x; 1.4122x over previous
//
#include <hip/hip_runtime.h>
#include <cstddef>

// VGG-16 fwd, batch=1. R5: separate kernels (R3 structure) + 2 blocks/CU convs.
//  - conv co-block 64 -> 32 (template CO): LDS <= 80KB -> 2 blocks/CU, grids 512
//  - proven dbuf + global_load_lds_dwordx4 + counted-vmcnt pipeline kept verbatim
//  - out-of-task staging waves -> LDS dump line (wave-uniform vmcnt)
//  - maxpool fused into L2/L4 conv epilogue (MODE 3)
//  - FC: fp32 GEMV, weight-BW-bound (~100us floor)

typedef __attribute__((ext_vector_type(8))) short short8;
typedef __attribute__((ext_vector_type(4))) float f32x4;

__device__ inline unsigned short f2bf(float f) {
    unsigned int u = __builtin_bit_cast(unsigned int, f);
    u += 0x7FFF + ((u >> 16) & 1);          // RNE
    return (unsigned short)(u >> 16);
}

// direct global->LDS 16B: LDS dest = M0 + lane*16 (wave-uniform base in m0)
__device__ __forceinline__ void gl_lds16(const void* src, unsigned m0v) {
    asm volatile("s_mov_b32 m0, %1\n\t"
                 "global_load_lds_dwordx4 %0, off"
                 :: "v"(src), "s"(m0v) : "memory");
}

// ---------------- fused weight transform: OIHW fp32 -> [pos][co][ci] bf16 ----
struct WtDesc { const float* src; unsigned dst; int cin; int cout; int blk0; };
struct WtArgs { WtDesc d[12]; };

__global__ __launch_bounds__(256)
void wt_all_k(WtArgs A, unsigned short* __restrict__ wt, unsigned short* __restrict__ guard)
{
    __shared__ unsigned short lds[4][9 * 520];     // per-wave [pos][ci], stride 520 pads banks
    const int tid = threadIdx.x, wv = tid >> 6, lane = tid & 63;
    if (blockIdx.x == 0 && tid < 128) guard[tid] = 0;

    int l = 0;
#pragma unroll
    for (int i = 1; i < 12; ++i) l = ((int)blockIdx.x >= A.d[i].blk0) ? i : l;
    const WtDesc D = A.d[l];
    const int co = ((int)blockIdx.x - D.blk0) * 4 + wv;
    const int n = D.cin * 9;
    const int cinP = D.cin + 8;

    // phase 1: coalesced float4 read of contiguous co-row, scatter to [pos][ci] in LDS
    const float4* src = (const float4*)(D.src + (size_t)co * n);
    for (int i = lane; i < (n >> 2); i += 64) {
        float4 v = src[i];
        unsigned short b[4] = {f2bf(v.x), f2bf(v.y), f2bf(v.z), f2bf(v.w)};
        const int f0 = i * 4;
#pragma unroll
        for (int k = 0; k < 4; ++k) {
            const int f = f0 + k, ci = f / 9, pos = f - ci * 9;
            lds[wv][pos * cinP + ci] = b[k];
        }
    }
    __syncthreads();
    // phase 2: coalesced bf16 writes, 8B per lane
    unsigned short* dstb = wt + D.dst;
#pragma unroll 1
    for (int pos = 0; pos < 9; ++pos) {
        unsigned short* drow = dstb + ((size_t)pos * D.cout + co) * D.cin;
        for (int c4 = lane; c4 < (D.cin >> 2); c4 += 64) {
            ushort4 u = *(const ushort4*)&lds[wv][pos * cinP + c4 * 4];
            *(ushort4*)(drow + c4 * 4) = u;
        }
    }
}

// ---------------- MFMA conv ----------------
// MODE: 0 relu+bf16 NHWC | 2 fp32 partial (ci-split) | 3 fused 2x2 maxpool+relu+bf16
// CO co-channels per block (32 -> 2 blocks/CU), 4 waves, wave tile CO x (PR/4*16)px
template<int PR, int CO, int MODE>
__global__ __launch_bounds__(256, 2)
void conv_mfma_k(const unsigned short* __restrict__ act,
                 const unsigned short* __restrict__ wt,
                 const unsigned short* __restrict__ guard,
                 void* __restrict__ outp,
                 int Cin, int Cout, int H, int W, int chunkCi)
{
    constexpr int NT = PR / 4;
    constexpr int MT = CO / 16;
    constexpr int ICELLS = (PR + 2) * 18;
    constexpr int ITASK = ICELLS * 4;                  // 16B tasks, input tile
    constexpr int ITIN = (ITASK + 255) / 256;
    constexpr int IBYTES = ((ITASK + 63) & ~63) * 16;  // per-buf, wave-rounded
    constexpr int WTASK = 9 * CO * 4;                  // 16B tasks, weights
    constexpr int WIT = (WTASK + 255) / 256;
    constexpr int WBYTES = 9 * CO * 64;                // per-buf
    constexpr int VL = WIT + ITIN;                     // loads per STAGE per thread

    __shared__ __align__(16) unsigned short wLds[2 * WBYTES / 2];   // [pos][co][ci32]
    __shared__ __align__(16) unsigned short iLds[2 * IBYTES / 2];   // [row][col18][ci32]
    __shared__ __align__(16) unsigned short dump[512];              // dummy-wave dest

    const int tid = threadIdx.x;
    const int lane = tid & 63, wv = tid >> 6;
    const int half = lane >> 4, l15 = lane & 15;
    const int tilesX = W >> 4;
    const int pY = blockIdx.x / tilesX, pX = blockIdx.x - pY * tilesX;
    const int y0 = pY * PR, x0 = pX * 16;
    const int cob = blockIdx.y, s = blockIdx.z;
    const int ciBeg = s * chunkCi;
    const int nCh = chunkCi >> 5;

    f32x4 acc[MT][NT];
#pragma unroll
    for (int mt = 0; mt < MT; ++mt)
#pragma unroll
        for (int nt = 0; nt < NT; ++nt) acc[mt][nt] = (f32x4){0.f, 0.f, 0.f, 0.f};

    auto STAGE = [&](int buf, int ci0) {
        const unsigned wB = (unsigned)(size_t)wLds + buf * WBYTES;
        const unsigned iB = (unsigned)(size_t)iLds + buf * IBYTES;
        const unsigned dB = (unsigned)(size_t)dump;
        // weights: 9 pos x CO co x 32 ci
#pragma unroll
        for (int it = 0; it < WIT; ++it) {
            const int idx = it * 256 + tid;
            const int cell = idx >> 2, q = idx & 3;
            const int pos = cell / CO, co = cell % CO;
            const bool real = idx < WTASK;
            const unsigned short* src = real ?
                wt + (size_t)(pos * Cout + cob * CO + co) * Cin + ci0 + q * 8 : guard;
            const bool eng = (it * 256 + wv * 64) < WTASK;     // wave-uniform
            gl_lds16(src, __builtin_amdgcn_readfirstlane(
                eng ? wB + (unsigned)(it * 4096 + wv * 1024) : dB));
        }
        // input halo tile: (PR+2) x 18 x 32ci, OOB lanes -> zero guard
#pragma unroll
        for (int it = 0; it < ITIN; ++it) {
            const int idx = it * 256 + tid;
            const int cell = idx >> 2, q = idx & 3;
            const int r = cell / 18, c = cell - r * 18;
            const int y = y0 - 1 + r, x = x0 - 1 + c;
            const bool ok = (idx < ITASK) & (y >= 0) & (y < H) & (x >= 0) & (x < W);
            const unsigned short* src = ok ?
                act + (size_t)(y * W + x) * Cin + ci0 + q * 8 : guard;
            const bool eng = (it * 256 + wv * 64) < ITASK;     // wave-uniform
            gl_lds16(src, __builtin_amdgcn_readfirstlane(
                eng ? iB + (unsigned)(it * 4096 + wv * 1024) : dB));
        }
    };

    STAGE(0, ciBeg);
    for (int t = 0; t < nCh; ++t) {
        const int buf = t & 1;
        if (t + 1 < nCh) {
            STAGE(buf ^ 1, ciBeg + ((t + 1) << 5));      // prefetch next chunk
            if constexpr (VL == 8)  asm volatile("s_waitcnt vmcnt(8)" ::: "memory");
            else if constexpr (VL == 11) asm volatile("s_waitcnt vmcnt(11)" ::: "memory");
            else asm volatile("s_waitcnt vmcnt(0)" ::: "memory");
        } else {
            asm volatile("s_waitcnt vmcnt(0)" ::: "memory");
        }
        __builtin_amdgcn_s_barrier();
        asm volatile("" ::: "memory");

        const unsigned short* wP = wLds + buf * (WBYTES / 2);
        const unsigned short* iP = iLds + buf * (IBYTES / 2);
#pragma unroll
        for (int ky = 0; ky < 3; ++ky)
#pragma unroll
        for (int kx = 0; kx < 3; ++kx) {
            const int pos = ky * 3 + kx;
            short8 a[MT];
#pragma unroll
            for (int mt = 0; mt < MT; ++mt)
                a[mt] = *(const short8*)&wP[((pos * CO) + (mt << 4) + l15) * 32 + half * 8];
#pragma unroll
            for (int nt = 0; nt < NT; ++nt) {
                const short8 b = *(const short8*)
                    &iP[((wv * NT + nt + ky) * 18 + l15 + kx) * 32 + half * 8];
#pragma unroll
                for (int mt = 0; mt < MT; ++mt)
                    acc[mt][nt] = __builtin_amdgcn_mfma_f32_16x16x32_bf16(a[mt], b, acc[mt][nt], 0, 0, 0);
            }
        }
        asm volatile("" ::: "memory");
        __builtin_amdgcn_s_barrier();
    }

    // ---- epilogue: D layout col(lane&15)=pixel-x, row((lane>>4)*4+reg)=co ----
    const int xg = x0 + l15;
    if (MODE == 3) {
        const int Wo = W >> 1;
#pragma unroll
        for (int mt = 0; mt < MT; ++mt)
#pragma unroll
        for (int nt = 0; nt < NT; nt += 2) {
            f32x4 a;
#pragma unroll
            for (int j = 0; j < 4; ++j) a[j] = fmaxf(acc[mt][nt][j], acc[mt][nt + 1][j]);
            f32x4 m;
#pragma unroll
            for (int j = 0; j < 4; ++j) m[j] = fmaxf(a[j], __shfl_xor(a[j], 1, 64));
            if ((l15 & 1) == 0) {
                const int yo = (y0 + wv * NT + nt) >> 1;
                const int xo = xg >> 1;
                const int co = cob * CO + (mt << 4) + half * 4;
                ushort4 u;
                u.x = f2bf(fmaxf(m[0], 0.f));
                u.y = f2bf(fmaxf(m[1], 0.f));
                u.z = f2bf(fmaxf(m[2], 0.f));
                u.w = f2bf(fmaxf(m[3], 0.f));
                *(ushort4*)((unsigned short*)outp + ((size_t)(yo * Wo + xo) * Cout + co)) = u;
            }
        }
    } else {
#pragma unroll
        for (int mt = 0; mt < MT; ++mt)
#pragma unroll
        for (int nt = 0; nt < NT; ++nt) {
            const int yg = y0 + wv * NT + nt;
            const int co = cob * CO + (mt << 4) + half * 4;
            const size_t base = (size_t)(yg * W + xg) * Cout + co;
            if (MODE == 2) {
                float4 v = make_float4(acc[mt][nt][0], acc[mt][nt][1], acc[mt][nt][2], acc[mt][nt][3]);
                *(float4*)((float*)outp + (size_t)s * Cout * H * W + base) = v;
            } else {
                ushort4 u;
                u.x = f2bf(fmaxf(acc[mt][nt][0], 0.f));
                u.y = f2bf(fmaxf(acc[mt][nt][1], 0.f));
                u.z = f2bf(fmaxf(acc[mt][nt][2], 0.f));
                u.w = f2bf(fmaxf(acc[mt][nt][3], 0.f));
                *(ushort4*)((unsigned short*)outp + base) = u;
            }
        }
    }
}

// ---------------- L1: fp32 vector conv (Cin=3), epilogue -> NHWC bf16+relu ----
#define TILE 16
#define COB  32
__global__ __launch_bounds__(256)
void conv1_k(const float* __restrict__ in, const float* __restrict__ wt,
             unsigned short* __restrict__ out)
{
    const int Cin = 3, H = 256, W = 256, HW = H * W;
    __shared__ float sIn[2][648];
    __shared__ float sWt[2][768];

    const int tid = threadIdx.x;
    const int bx = blockIdx.x, by = blockIdx.y, co_blk = blockIdx.z;
    const int co_grp = tid >> 6;
    const int lane = tid & 63;
    const int tx = lane & 7, ty = lane >> 3;
    const int x0 = bx * TILE, y0 = by * TILE;

    int iLdsI[3], iG[3], iSub[3]; bool iOk[3];
    int wLdsI[3], wG[3], wSub[3]; bool wOk[3];
#pragma unroll
    for (int j = 0; j < 3; ++j) {
        int i = tid + j * 256;
        iOk[j] = false; iLdsI[j] = 0; iG[j] = 0; iSub[j] = 0;
        if (i < 648) {
            int sub = i / 324; int r = i - sub * 324;
            int iy = r / 18;   int ix = r - iy * 18;
            iSub[j] = sub; iLdsI[j] = sub * 324 + r;
            int y = y0 - 1 + iy, x = x0 - 1 + ix;
            if (y >= 0 && y < H && x >= 0 && x < W) { iOk[j] = true; iG[j] = sub * HW + y * W + x; }
        }
        wOk[j] = false; wLdsI[j] = 0; wG[j] = 0; wSub[j] = 0;
        if (i < 576) {
            int sub = i / 288; int r = i - sub * 288;
            int col = r / 9;   int k = r - col * 9;
            wSub[j] = sub; wLdsI[j] = sub * 384 + col * 12 + k;
            wG[j] = ((co_blk * COB + col) * Cin + sub) * 9 + k;
            wOk[j] = true;
        }
    }

    float4 acc[8];
#pragma unroll
    for (int c = 0; c < 8; ++c) acc[c] = make_float4(0.f, 0.f, 0.f, 0.f);

    const int nSteps = 2;   // ci pairs (0,1),(2,-)
    float rIn[3], rWt[3];
    {
#pragma unroll
        for (int j = 0; j < 3; ++j)
            rIn[j] = (iOk[j] && iSub[j] < 3) ? in[iG[j]] : 0.f;
#pragma unroll
        for (int j = 0; j < 3; ++j)
            rWt[j] = (wOk[j] && wSub[j] < 3) ? wt[wG[j]] : 0.f;
#pragma unroll
        for (int j = 0; j < 3; ++j) { if (tid + j * 256 < 648) sIn[0][iLdsI[j]] = rIn[j]; }
#pragma unroll
        for (int j = 0; j < 3; ++j) { if (tid + j * 256 < 576) sWt[0][wLdsI[j]] = rWt[j]; }
    }

    for (int t = 0; t < nSteps; ++t) {
        __syncthreads();
        const bool more = (t + 1) < nSteps;
        if (more) {
            const int ci0 = 2;
#pragma unroll
            for (int j = 0; j < 3; ++j)
                rIn[j] = (iOk[j] && (ci0 + iSub[j]) < 3) ? in[(size_t)ci0 * HW + iG[j]] : 0.f;
#pragma unroll
            for (int j = 0; j < 3; ++j)
                rWt[j] = (wOk[j] && (ci0 + wSub[j]) < 3) ? wt[(size_t)ci0 * 9 + wG[j]] : 0.f;
        }
        const int buf = t & 1;
        const float* sI = sIn[buf];
        const float* sW = sWt[buf];
#pragma unroll
        for (int sub = 0; sub < 2; ++sub) {
            float wv[4][4];
            const float* sp = sI + sub * 324 + (2 * ty) * 18 + 2 * tx;
#pragma unroll
            for (int r = 0; r < 4; ++r) {
                float2 a = *(const float2*)(sp + r * 18);
                float2 b = *(const float2*)(sp + r * 18 + 2);
                wv[r][0] = a.x; wv[r][1] = a.y; wv[r][2] = b.x; wv[r][3] = b.y;
            }
#pragma unroll
            for (int c = 0; c < 8; ++c) {
                const float* wp = sW + sub * 384 + (co_grp * 8 + c) * 12;
                float4 w0 = *(const float4*)wp;
                float4 w1 = *(const float4*)(wp + 4);
                float  w8 = wp[8];
                const float wk[9] = {w0.x, w0.y, w0.z, w0.w, w1.x, w1.y, w1.z, w1.w, w8};
                float* ac = (float*)&acc[c];
#pragma unroll
                for (int py = 0; py < 2; ++py)
#pragma unroll
                for (int px = 0; px < 2; ++px) {
                    float sacc = ac[py * 2 + px];
#pragma unroll
                    for (int kk = 0; kk < 9; ++kk)
                        sacc = fmaf(wv[py + kk / 3][px + kk % 3], wk[kk], sacc);
                    ac[py * 2 + px] = sacc;
                }
            }
        }
        if (more) {
#pragma unroll
            for (int j = 0; j < 3; ++j) { if (tid + j * 256 < 648) sIn[buf ^ 1][iLdsI[j]] = rIn[j]; }
#pragma unroll
            for (int j = 0; j < 3; ++j) { if (tid + j * 256 < 576) sWt[buf ^ 1][wLdsI[j]] = rWt[j]; }
        }
    }

    const int co0 = co_blk * COB + co_grp * 8;   // 8 consecutive co
#pragma unroll
    for (int py = 0; py < 2; ++py)
#pragma unroll
    for (int px = 0; px < 2; ++px) {
        const int y = y0 + 2 * ty + py, x = x0 + 2 * tx + px;
        unsigned short u8[8];
#pragma unroll
        for (int c = 0; c < 8; ++c)
            u8[c] = f2bf(fmaxf(((const float*)&acc[c])[py * 2 + px], 0.f));
        *(uint4*)(out + (size_t)(y * W + x) * 64 + co0) = *(uint4*)u8;
    }
}

// ---------------- aux kernels ----------------
// sum S fp32 partials + relu -> bf16 NHWC
__global__ __launch_bounds__(256)
void reduce_cvt_k(const float* __restrict__ P, unsigned short* __restrict__ out,
                  int n4, int S)
{
    int i = blockIdx.x * 256 + threadIdx.x;
    if (i >= n4) return;
    const float4* p4 = (const float4*)P;
    float4 a = p4[i];
    for (int s = 1; s < S; ++s) {
        float4 b = p4[(size_t)i + (size_t)s * n4];
        a.x += b.x; a.y += b.y; a.z += b.z; a.w += b.w;
    }
    ushort4 u;
    u.x = f2bf(fmaxf(a.x, 0.f)); u.y = f2bf(fmaxf(a.y, 0.f));
    u.z = f2bf(fmaxf(a.z, 0.f)); u.w = f2bf(fmaxf(a.w, 0.f));
    *(ushort4*)(out + (size_t)i * 4) = u;
}

// sum S fp32 partials, 2x2 maxpool, relu -> bf16 NHWC
__global__ __launch_bounds__(256)
void reduce_pool_cvt_k(const float* __restrict__ P, unsigned short* __restrict__ out,
                       int C, int H, int W, int S)
{
    const int C4 = C >> 2, Wo = W >> 1, Ho = H >> 1;
    const int n = Ho * Wo * C4;
    int i = blockIdx.x * 256 + threadIdx.x;
    if (i >= n) return;
    const int c4 = i % C4, p = i / C4;
    const int yo = p / Wo, xo = p - yo * Wo;
    const size_t CHW = (size_t)C * H * W;
    const size_t b = (size_t)(2 * yo * W + 2 * xo) * C + c4 * 4;
    float4 v[4] = {{0,0,0,0},{0,0,0,0},{0,0,0,0},{0,0,0,0}};
    for (int s = 0; s < S; ++s) {
        const float* ps = P + s * CHW;
        float4 t0 = *(const float4*)(ps + b);
        float4 t1 = *(const float4*)(ps + b + C);
        float4 t2 = *(const float4*)(ps + b + (size_t)W * C);
        float4 t3 = *(const float4*)(ps + b + (size_t)W * C + C);
        v[0].x += t0.x; v[0].y += t0.y; v[0].z += t0.z; v[0].w += t0.w;
        v[1].x += t1.x; v[1].y += t1.y; v[1].z += t1.z; v[1].w += t1.w;
        v[2].x += t2.x; v[2].y += t2.y; v[2].z += t2.z; v[2].w += t2.w;
        v[3].x += t3.x; v[3].y += t3.y; v[3].z += t3.z; v[3].w += t3.w;
    }
    ushort4 u;
    u.x = f2bf(fmaxf(fmaxf(fmaxf(v[0].x, v[1].x), fmaxf(v[2].x, v[3].x)), 0.f));
    u.y = f2bf(fmaxf(fmaxf(fmaxf(v[0].y, v[1].y), fmaxf(v[2].y, v[3].y)), 0.f));
    u.z = f2bf(fmaxf(fmaxf(fmaxf(v[0].z, v[1].z), fmaxf(v[2].z, v[3].z)), 0.f));
    u.w = f2bf(fmaxf(fmaxf(fmaxf(v[0].w, v[1].w), fmaxf(v[2].w, v[3].w)), 0.f));
    *(ushort4*)(out + (size_t)p * C + c4 * 4) = u;
}

// L13: sum 16 partials, pool, relu -> fp32 NCHW flatten order
__global__ __launch_bounds__(256)
void reduce_pool_f32_k(const float* __restrict__ P, float* __restrict__ out,
                       int C, int H, int W, int S)
{
    const int Wo = W >> 1, Ho = H >> 1;
    const int n = Ho * Wo * C;
    int i = blockIdx.x * 256 + threadIdx.x;
    if (i >= n) return;
    const int c = i % C, p = i / C;
    const int yo = p / Wo, xo = p - yo * Wo;
    const size_t CHW = (size_t)C * H * W;
    float v0 = 0.f, v1 = 0.f, v2 = 0.f, v3 = 0.f;
    const size_t b = (size_t)(2 * yo * W + 2 * xo) * C + c;
    for (int s = 0; s < S; ++s) {
        const float* ps = P + s * CHW;
        v0 += ps[b]; v1 += ps[b + C]; v2 += ps[b + (size_t)W * C]; v3 += ps[b + (size_t)W * C + C];
    }
    out[(size_t)c * (Ho * Wo) + p] = fmaxf(fmaxf(fmaxf(v0, v1), fmaxf(v2, v3)), 0.f);
}

// ---------------- FC GEMV (fp32, weight-BW-bound) ----------------
__global__ __launch_bounds__(256)
void gemv_k(const float* __restrict__ Wm, const float* __restrict__ xv,
            float* __restrict__ y, int K)
{
    __shared__ float red[4];
    const int tid = threadIdx.x;
    const float4* row = (const float4*)(Wm + (size_t)blockIdx.x * K);
    const float4* x4  = (const float4*)xv;
    const int K4 = K >> 2;
    float sum = 0.f;
    for (int i = tid; i < K4; i += 256) {
        float4 a = row[i], b = x4[i];
        sum += a.x * b.x + a.y * b.y + a.z * b.z + a.w * b.w;
    }
#pragma unroll
    for (int off = 32; off > 0; off >>= 1) sum += __shfl_down(sum, off, 64);
    if ((tid & 63) == 0) red[tid >> 6] = sum;
    __syncthreads();
    if (tid == 0) y[blockIdx.x] = red[0] + red[1] + red[2] + red[3];
}

// ---------------- launcher ----------------
extern "C" void kernel_launch(void* const* d_in, const int* in_sizes, int n_in,
                              void* d_out, int out_size, void* d_ws, size_t ws_size,
                              hipStream_t stream)
{
    (void)in_sizes; (void)n_in; (void)out_size; (void)ws_size;
    const float* x = (const float*)d_in[0];
    const float* cw[13];
    for (int i = 0; i < 13; ++i) cw[i] = (const float*)d_in[5 + i];
    const float* fw1 = (const float*)d_in[18];
    const float* fw2 = (const float*)d_in[19];
    const float* fw3 = (const float*)d_in[20];
    float* outp = (float*)d_out;

    // layers 2..13 (index 0..11 here)
    static const int CIN[12]  = {64, 64, 128, 128, 256, 256, 256, 512, 512, 512, 512, 512};
    static const int COUT[12] = {64, 128, 128, 256, 256, 256, 512, 512, 512, 512, 512, 512};

    char* ws = (char*)d_ws;
    size_t wOff[12]; size_t o = 0;
    for (int i = 0; i < 12; ++i) { wOff[i] = o; o += (size_t)9 * COUT[i] * CIN[i]; }
    unsigned short* WT = (unsigned short*)ws;               // 29.4 MB bf16
    unsigned short* guardp = WT + o;                        // 256 B zero guard
    size_t ao = ((o + 128) * 2 + 255) & ~(size_t)255;
    unsigned short* bA = (unsigned short*)(ws + ao);        // 8.39 MB
    unsigned short* bB = (unsigned short*)(ws + ao + 8388608);
    char* Pr = ws + ao + 2 * 8388608;                       // 8.39 MB partials
    float* Pf = (float*)Pr;
    float* fcIn = (float*)bA;                               // L13 result (128 KB)
    float* F1 = (float*)bB;
    float* F2 = F1 + 4096;

    // fused weight transform (also zeroes the halo guard)
    WtArgs wa; int blk = 0;
    {
        size_t oo = 0;
        for (int i = 0; i < 12; ++i) {
            wa.d[i].src = cw[i + 1];
            wa.d[i].dst = (unsigned)oo;
            wa.d[i].cin = CIN[i];
            wa.d[i].cout = COUT[i];
            wa.d[i].blk0 = blk;
            oo += (size_t)9 * COUT[i] * CIN[i];
            blk += COUT[i] / 4;
        }
    }
    wt_all_k<<<blk, 256, 0, stream>>>(wa, WT, guardp);

    // L1: fp32 vector conv 3->64 @256^2, out NHWC bf16
    conv1_k<<<dim3(16, 16, 2), 256, 0, stream>>>(x, cw[0], bA);

    // L2: 64->64 @256^2, fused pool -> bB @128^2
    conv_mfma_k<16, 32, 3><<<dim3(256, 2, 1), 256, 0, stream>>>(bA, WT + wOff[0], guardp, bB, 64, 64, 256, 256, 64);
    // L3: 64->128 @128^2 -> bA
    conv_mfma_k<8, 32, 0><<<dim3(128, 4, 1), 256, 0, stream>>>(bB, WT + wOff[1], guardp, bA, 64, 128, 128, 128, 64);
    // L4: 128->128 @128^2, fused pool -> bB @64^2
    conv_mfma_k<8, 32, 3><<<dim3(128, 4, 1), 256, 0, stream>>>(bA, WT + wOff[2], guardp, bB, 128, 128, 128, 128, 128);
    // L5: 128->256 @64^2, S=2
    conv_mfma_k<8, 32, 2><<<dim3(32, 8, 2), 256, 0, stream>>>(bB, WT + wOff[3], guardp, Pf, 128, 256, 64, 64, 64);
    reduce_cvt_k<<<(262144 + 255) / 256, 256, 0, stream>>>(Pf, bA, 262144, 2);
    // L6: 256->256 @64^2, S=2
    conv_mfma_k<8, 32, 2><<<dim3(32, 8, 2), 256, 0, stream>>>(bA, WT + wOff[4], guardp, Pf, 256, 256, 64, 64, 128);
    reduce_cvt_k<<<(262144 + 255) / 256, 256, 0, stream>>>(Pf, bB, 262144, 2);
    // L7: 256->256 @64^2, S=2, pool -> 32^2
    conv_mfma_k<8, 32, 2><<<dim3(32, 8, 2), 256, 0, stream>>>(bB, WT + wOff[5], guardp, Pf, 256, 256, 64, 64, 128);
    reduce_pool_cvt_k<<<(65536 + 255) / 256, 256, 0, stream>>>(Pf, bA, 256, 64, 64, 2);
    // L8: 256->512 @32^2, S=4
    conv_mfma_k<8, 32, 2><<<dim3(8, 16, 4), 256, 0, stream>>>(bA, WT + wOff[6], guardp, Pf, 256, 512, 32, 32, 64);
    reduce_cvt_k<<<(131072 + 255) / 256, 256, 0, stream>>>(Pf, bB, 131072, 4);
    // L9: 512->512 @32^2, S=4
    conv_mfma_k<8, 32, 2><<<dim3(8, 16, 4), 256, 0, stream>>>(bB, WT + wOff[7], guardp, Pf, 512, 512, 32, 32, 128);
    reduce_cvt_k<<<(131072 + 255) / 256, 256, 0, stream>>>(Pf, bA, 131072, 4);
    // L10: 512->512 @32^2, S=4, pool -> 16^2
    conv_mfma_k<8, 32, 2><<<dim3(8, 16, 4), 256, 0, stream>>>(bA, WT + wOff[8], guardp, Pf, 512, 512, 32, 32, 128);
    reduce_pool_cvt_k<<<(32768 + 255) / 256, 256, 0, stream>>>(Pf, bB, 512, 32, 32, 4);
    // L11: 512->512 @16^2, S=16
    conv_mfma_k<8, 32, 2><<<dim3(2, 16, 16), 256, 0, stream>>>(bB, WT + wOff[9], guardp, Pf, 512, 512, 16, 16, 32);
    reduce_cvt_k<<<(32768 + 255) / 256, 256, 0, stream>>>(Pf, bA, 32768, 16);
    // L12
    conv_mfma_k<8, 32, 2><<<dim3(2, 16, 16), 256, 0, stream>>>(bA, WT + wOff[10], guardp, Pf, 512, 512, 16, 16, 32);
    reduce_cvt_k<<<(32768 + 255) / 256, 256, 0, stream>>>(Pf, bB, 32768, 16);
    // L13: S=16, pool -> fp32 NCHW flatten [512][8][8]
    conv_mfma_k<8, 32, 2><<<dim3(2, 16, 16), 256, 0, stream>>>(bB, WT + wOff[11], guardp, Pf, 512, 512, 16, 16, 32);
    reduce_pool_f32_k<<<(32768 + 255) / 256, 256, 0, stream>>>(Pf, fcIn, 512, 16, 16, 16);

    // FC head (fp32, HBM-bound on weights)
    gemv_k<<<4096, 256, 0, stream>>>(fw1, fcIn, F1, 32768);
    gemv_k<<<4096, 256, 0, stream>>>(fw2, F1, F2, 4096);
    gemv_k<<<1000, 256, 0, stream>>>(fw3, F2, outp, 4096);
}

// Round 4
// 940.479 us; speedup vs baseline: 1.4547x; 1.0301x over previous
//
#include <hip/hip_runtime.h>
#include <cstddef>

// VGG-16 fwd, batch=1. R6: no ci-split — every conv writes bf16 (or pooled) directly.
//  - 12 conv layers all MODE 0/3/4, nCh=2..16 K-chunks -> dbuf pipeline works
//  - PR=4 tile keeps 256-block grids on 32^2 layers; L13 fused pool+fp32 NCHW (MODE 4)
//  - dispatches 27 -> 17 (wt, conv1, 12 convs, 3 gemv); reduce kernels deleted
//  - staging via global_load_lds_dwordx4, counted vmcnt, raw s_barrier (proven R3/R5)
//  - FC: fp32 GEMV, weight-BW-bound (~100us floor)

typedef __attribute__((ext_vector_type(8))) short short8;
typedef __attribute__((ext_vector_type(4))) float f32x4;

__device__ inline unsigned short f2bf(float f) {
    unsigned int u = __builtin_bit_cast(unsigned int, f);
    u += 0x7FFF + ((u >> 16) & 1);          // RNE
    return (unsigned short)(u >> 16);
}

// direct global->LDS 16B: LDS dest = M0 + lane*16 (wave-uniform base in m0)
__device__ __forceinline__ void gl_lds16(const void* src, unsigned m0v) {
    asm volatile("s_mov_b32 m0, %1\n\t"
                 "global_load_lds_dwordx4 %0, off"
                 :: "v"(src), "s"(m0v) : "memory");
}

// ---------------- fused weight transform: OIHW fp32 -> [pos][co][ci] bf16 ----
struct WtDesc { const float* src; unsigned dst; int cin; int cout; int blk0; };
struct WtArgs { WtDesc d[12]; };

__global__ __launch_bounds__(256)
void wt_all_k(WtArgs A, unsigned short* __restrict__ wt, unsigned short* __restrict__ guard)
{
    __shared__ unsigned short lds[4][9 * 520];     // per-wave [pos][ci], stride 520 pads banks
    const int tid = threadIdx.x, wv = tid >> 6, lane = tid & 63;
    if (blockIdx.x == 0 && tid < 128) guard[tid] = 0;

    int l = 0;
#pragma unroll
    for (int i = 1; i < 12; ++i) l = ((int)blockIdx.x >= A.d[i].blk0) ? i : l;
    const WtDesc D = A.d[l];
    const int co = ((int)blockIdx.x - D.blk0) * 4 + wv;
    const int n = D.cin * 9;
    const int cinP = D.cin + 8;

    // phase 1: coalesced float4 read of contiguous co-row, scatter to [pos][ci] in LDS
    const float4* src = (const float4*)(D.src + (size_t)co * n);
    for (int i = lane; i < (n >> 2); i += 64) {
        float4 v = src[i];
        unsigned short b[4] = {f2bf(v.x), f2bf(v.y), f2bf(v.z), f2bf(v.w)};
        const int f0 = i * 4;
#pragma unroll
        for (int k = 0; k < 4; ++k) {
            const int f = f0 + k, ci = f / 9, pos = f - ci * 9;
            lds[wv][pos * cinP + ci] = b[k];
        }
    }
    __syncthreads();
    // phase 2: coalesced bf16 writes, 8B per lane
    unsigned short* dstb = wt + D.dst;
#pragma unroll 1
    for (int pos = 0; pos < 9; ++pos) {
        unsigned short* drow = dstb + ((size_t)pos * D.cout + co) * D.cin;
        for (int c4 = lane; c4 < (D.cin >> 2); c4 += 64) {
            ushort4 u = *(const ushort4*)&lds[wv][pos * cinP + c4 * 4];
            *(ushort4*)(drow + c4 * 4) = u;
        }
    }
}

// ---------------- MFMA conv ----------------
// MODE: 0 relu+bf16 NHWC | 3 fused 2x2 maxpool+relu+bf16 NHWC | 4 pool+relu+fp32 NCHW
// CO=32 co-channels/block, 4 waves; wave tile CO x (PR/4*16)px (PR=4: CO x 16px/wave-row)
template<int PR, int CO, int MODE>
__global__ __launch_bounds__(256, 2)
void conv_mfma_k(const unsigned short* __restrict__ act,
                 const unsigned short* __restrict__ wt,
                 const unsigned short* __restrict__ guard,
                 void* __restrict__ outp,
                 int Cin, int Cout, int H, int W)
{
    constexpr int NT = (PR + 3) / 4;                   // row-tiles per wave (PR=4 -> 1)
    constexpr int MT = CO / 16;
    constexpr int ICELLS = (PR + 2) * 18;
    constexpr int ITASK = ICELLS * 4;                  // 16B tasks, input tile
    constexpr int ITIN = (ITASK + 255) / 256;
    constexpr int IBYTES = ((ITASK + 63) & ~63) * 16;  // per-buf, wave-rounded
    constexpr int WTASK = 9 * CO * 4;                  // 16B tasks, weights
    constexpr int WIT = (WTASK + 255) / 256;
    constexpr int WBYTES = 9 * CO * 64;                // per-buf
    constexpr int VL = WIT + ITIN;                     // loads per STAGE per thread
    static_assert(VL == 7 || VL == 8 || VL == 11, "unexpected stage depth");
    static_assert(MODE == 0 || ((MODE == 3 || MODE == 4) && (NT % 2) == 0), "pool needs even NT");

    __shared__ __align__(16) unsigned short wLds[2 * WBYTES / 2];   // [pos][co][ci32]
    __shared__ __align__(16) unsigned short iLds[2 * IBYTES / 2];   // [row][col18][ci32]
    __shared__ __align__(16) unsigned short dump[512];              // dummy-wave dest

    const int tid = threadIdx.x;
    const int lane = tid & 63, wv = tid >> 6;
    const int half = lane >> 4, l15 = lane & 15;
    const int tilesX = W >> 4;
    const int pY = blockIdx.x / tilesX, pX = blockIdx.x - pY * tilesX;
    const int y0 = pY * PR, x0 = pX * 16;
    const int cob = blockIdx.y;
    const int nCh = Cin >> 5;

    f32x4 acc[MT][NT];
#pragma unroll
    for (int mt = 0; mt < MT; ++mt)
#pragma unroll
        for (int nt = 0; nt < NT; ++nt) acc[mt][nt] = (f32x4){0.f, 0.f, 0.f, 0.f};

    auto STAGE = [&](int buf, int ci0) {
        const unsigned wB = (unsigned)(size_t)wLds + buf * WBYTES;
        const unsigned iB = (unsigned)(size_t)iLds + buf * IBYTES;
        const unsigned dB = (unsigned)(size_t)dump;
        // weights: 9 pos x CO co x 32 ci
#pragma unroll
        for (int it = 0; it < WIT; ++it) {
            const int idx = it * 256 + tid;
            const int cell = idx >> 2, q = idx & 3;
            const int pos = cell / CO, co = cell % CO;
            const bool real = idx < WTASK;
            const unsigned short* src = real ?
                wt + (size_t)(pos * Cout + cob * CO + co) * Cin + ci0 + q * 8 : guard;
            const bool eng = (it * 256 + wv * 64) < WTASK;     // wave-uniform
            gl_lds16(src, __builtin_amdgcn_readfirstlane(
                eng ? wB + (unsigned)(it * 4096 + wv * 1024) : dB));
        }
        // input halo tile: (PR+2) x 18 x 32ci, OOB lanes -> zero guard
#pragma unroll
        for (int it = 0; it < ITIN; ++it) {
            const int idx = it * 256 + tid;
            const int cell = idx >> 2, q = idx & 3;
            const int r = cell / 18, c = cell - r * 18;
            const int y = y0 - 1 + r, x = x0 - 1 + c;
            const bool ok = (idx < ITASK) & (y >= 0) & (y < H) & (x >= 0) & (x < W);
            const unsigned short* src = ok ?
                act + (size_t)(y * W + x) * Cin + ci0 + q * 8 : guard;
            const bool eng = (it * 256 + wv * 64) < ITASK;     // wave-uniform
            gl_lds16(src, __builtin_amdgcn_readfirstlane(
                eng ? iB + (unsigned)(it * 4096 + wv * 1024) : dB));
        }
    };

    STAGE(0, 0);
    for (int t = 0; t < nCh; ++t) {
        const int buf = t & 1;
        if (t + 1 < nCh) {
            STAGE(buf ^ 1, (t + 1) << 5);                // prefetch next chunk
            if constexpr (VL == 7)  asm volatile("s_waitcnt vmcnt(7)" ::: "memory");
            else if constexpr (VL == 8)  asm volatile("s_waitcnt vmcnt(8)" ::: "memory");
            else asm volatile("s_waitcnt vmcnt(11)" ::: "memory");
        } else {
            asm volatile("s_waitcnt vmcnt(0)" ::: "memory");
        }
        __builtin_amdgcn_s_barrier();
        asm volatile("" ::: "memory");

        const unsigned short* wP = wLds + buf * (WBYTES / 2);
        const unsigned short* iP = iLds + buf * (IBYTES / 2);
#pragma unroll
        for (int ky = 0; ky < 3; ++ky)
#pragma unroll
        for (int kx = 0; kx < 3; ++kx) {
            const int pos = ky * 3 + kx;
            short8 a[MT];
#pragma unroll
            for (int mt = 0; mt < MT; ++mt)
                a[mt] = *(const short8*)&wP[((pos * CO) + (mt << 4) + l15) * 32 + half * 8];
#pragma unroll
            for (int nt = 0; nt < NT; ++nt) {
                const short8 b = *(const short8*)
                    &iP[((wv * NT + nt + ky) * 18 + l15 + kx) * 32 + half * 8];
#pragma unroll
                for (int mt = 0; mt < MT; ++mt)
                    acc[mt][nt] = __builtin_amdgcn_mfma_f32_16x16x32_bf16(a[mt], b, acc[mt][nt], 0, 0, 0);
            }
        }
        asm volatile("" ::: "memory");
        __builtin_amdgcn_s_barrier();
    }

    // ---- epilogue: D layout col(lane&15)=pixel-x, row((lane>>4)*4+reg)=co ----
    const int xg = x0 + l15;
    if constexpr (MODE == 3 || MODE == 4) {
        const int Wo = W >> 1;
#pragma unroll
        for (int mt = 0; mt < MT; ++mt)
#pragma unroll
        for (int nt = 0; nt < NT; nt += 2) {
            f32x4 a;
#pragma unroll
            for (int j = 0; j < 4; ++j) a[j] = fmaxf(acc[mt][nt][j], acc[mt][nt + 1][j]);
            f32x4 m;
#pragma unroll
            for (int j = 0; j < 4; ++j) m[j] = fmaxf(a[j], __shfl_xor(a[j], 1, 64));
            if ((l15 & 1) == 0) {
                const int yo = (y0 + wv * NT + nt) >> 1;
                const int xo = xg >> 1;
                const int co = cob * CO + (mt << 4) + half * 4;
                if constexpr (MODE == 3) {
                    ushort4 u;
                    u.x = f2bf(fmaxf(m[0], 0.f));
                    u.y = f2bf(fmaxf(m[1], 0.f));
                    u.z = f2bf(fmaxf(m[2], 0.f));
                    u.w = f2bf(fmaxf(m[3], 0.f));
                    *(ushort4*)((unsigned short*)outp + ((size_t)(yo * Wo + xo) * Cout + co)) = u;
                } else {  // MODE 4: fp32 NCHW flatten [Cout][Ho][Wo]
                    const int Ho = W >> 1;  (void)Ho;
                    float* op = (float*)outp;
                    const int hw = (W >> 1) * (W >> 1);
#pragma unroll
                    for (int j = 0; j < 4; ++j)
                        op[(size_t)(co + j) * hw + yo * Wo + xo] = fmaxf(m[j], 0.f);
                }
            }
        }
    } else {
#pragma unroll
        for (int mt = 0; mt < MT; ++mt)
#pragma unroll
        for (int nt = 0; nt < NT; ++nt) {
            const int yg = y0 + wv * NT + nt;
            const int co = cob * CO + (mt << 4) + half * 4;
            const size_t base = (size_t)(yg * W + xg) * Cout + co;
            ushort4 u;
            u.x = f2bf(fmaxf(acc[mt][nt][0], 0.f));
            u.y = f2bf(fmaxf(acc[mt][nt][1], 0.f));
            u.z = f2bf(fmaxf(acc[mt][nt][2], 0.f));
            u.w = f2bf(fmaxf(acc[mt][nt][3], 0.f));
            *(ushort4*)((unsigned short*)outp + base) = u;
        }
    }
}

// ---------------- L1: fp32 vector conv (Cin=3), epilogue -> NHWC bf16+relu ----
#define TILE 16
#define COB  32
__global__ __launch_bounds__(256)
void conv1_k(const float* __restrict__ in, const float* __restrict__ wt,
             unsigned short* __restrict__ out)
{
    const int Cin = 3, H = 256, W = 256, HW = H * W;
    __shared__ float sIn[2][648];
    __shared__ float sWt[2][768];

    const int tid = threadIdx.x;
    const int bx = blockIdx.x, by = blockIdx.y, co_blk = blockIdx.z;
    const int co_grp = tid >> 6;
    const int lane = tid & 63;
    const int tx = lane & 7, ty = lane >> 3;
    const int x0 = bx * TILE, y0 = by * TILE;

    int iLdsI[3], iG[3], iSub[3]; bool iOk[3];
    int wLdsI[3], wG[3], wSub[3]; bool wOk[3];
#pragma unroll
    for (int j = 0; j < 3; ++j) {
        int i = tid + j * 256;
        iOk[j] = false; iLdsI[j] = 0; iG[j] = 0; iSub[j] = 0;
        if (i < 648) {
            int sub = i / 324; int r = i - sub * 324;
            int iy = r / 18;   int ix = r - iy * 18;
            iSub[j] = sub; iLdsI[j] = sub * 324 + r;
            int y = y0 - 1 + iy, x = x0 - 1 + ix;
            if (y >= 0 && y < H && x >= 0 && x < W) { iOk[j] = true; iG[j] = sub * HW + y * W + x; }
        }
        wOk[j] = false; wLdsI[j] = 0; wG[j] = 0; wSub[j] = 0;
        if (i < 576) {
            int sub = i / 288; int r = i - sub * 288;
            int col = r / 9;   int k = r - col * 9;
            wSub[j] = sub; wLdsI[j] = sub * 384 + col * 12 + k;
            wG[j] = ((co_blk * COB + col) * Cin + sub) * 9 + k;
            wOk[j] = true;
        }
    }

    float4 acc[8];
#pragma unroll
    for (int c = 0; c < 8; ++c) acc[c] = make_float4(0.f, 0.f, 0.f, 0.f);

    const int nSteps = 2;   // ci pairs (0,1),(2,-)
    float rIn[3], rWt[3];
    {
#pragma unroll
        for (int j = 0; j < 3; ++j)
            rIn[j] = (iOk[j] && iSub[j] < 3) ? in[iG[j]] : 0.f;
#pragma unroll
        for (int j = 0; j < 3; ++j)
            rWt[j] = (wOk[j] && wSub[j] < 3) ? wt[wG[j]] : 0.f;
#pragma unroll
        for (int j = 0; j < 3; ++j) { if (tid + j * 256 < 648) sIn[0][iLdsI[j]] = rIn[j]; }
#pragma unroll
        for (int j = 0; j < 3; ++j) { if (tid + j * 256 < 576) sWt[0][wLdsI[j]] = rWt[j]; }
    }

    for (int t = 0; t < nSteps; ++t) {
        __syncthreads();
        const bool more = (t + 1) < nSteps;
        if (more) {
            const int ci0 = 2;
#pragma unroll
            for (int j = 0; j < 3; ++j)
                rIn[j] = (iOk[j] && (ci0 + iSub[j]) < 3) ? in[(size_t)ci0 * HW + iG[j]] : 0.f;
#pragma unroll
            for (int j = 0; j < 3; ++j)
                rWt[j] = (wOk[j] && (ci0 + wSub[j]) < 3) ? wt[(size_t)ci0 * 9 + wG[j]] : 0.f;
        }
        const int buf = t & 1;
        const float* sI = sIn[buf];
        const float* sW = sWt[buf];
#pragma unroll
        for (int sub = 0; sub < 2; ++sub) {
            float wv[4][4];
            const float* sp = sI + sub * 324 + (2 * ty) * 18 + 2 * tx;
#pragma unroll
            for (int r = 0; r < 4; ++r) {
                float2 a = *(const float2*)(sp + r * 18);
                float2 b = *(const float2*)(sp + r * 18 + 2);
                wv[r][0] = a.x; wv[r][1] = a.y; wv[r][2] = b.x; wv[r][3] = b.y;
            }
#pragma unroll
            for (int c = 0; c < 8; ++c) {
                const float* wp = sW + sub * 384 + (co_grp * 8 + c) * 12;
                float4 w0 = *(const float4*)wp;
                float4 w1 = *(const float4*)(wp + 4);
                float  w8 = wp[8];
                const float wk[9] = {w0.x, w0.y, w0.z, w0.w, w1.x, w1.y, w1.z, w1.w, w8};
                float* ac = (float*)&acc[c];
#pragma unroll
                for (int py = 0; py < 2; ++py)
#pragma unroll
                for (int px = 0; px < 2; ++px) {
                    float sacc = ac[py * 2 + px];
#pragma unroll
                    for (int kk = 0; kk < 9; ++kk)
                        sacc = fmaf(wv[py + kk / 3][px + kk % 3], wk[kk], sacc);
                    ac[py * 2 + px] = sacc;
                }
            }
        }
        if (more) {
#pragma unroll
            for (int j = 0; j < 3; ++j) { if (tid + j * 256 < 648) sIn[buf ^ 1][iLdsI[j]] = rIn[j]; }
#pragma unroll
            for (int j = 0; j < 3; ++j) { if (tid + j * 256 < 576) sWt[buf ^ 1][wLdsI[j]] = rWt[j]; }
        }
    }

    const int co0 = co_blk * COB + co_grp * 8;   // 8 consecutive co
#pragma unroll
    for (int py = 0; py < 2; ++py)
#pragma unroll
    for (int px = 0; px < 2; ++px) {
        const int y = y0 + 2 * ty + py, x = x0 + 2 * tx + px;
        unsigned short u8[8];
#pragma unroll
        for (int c = 0; c < 8; ++c)
            u8[c] = f2bf(fmaxf(((const float*)&acc[c])[py * 2 + px], 0.f));
        *(uint4*)(out + (size_t)(y * W + x) * 64 + co0) = *(uint4*)u8;
    }
}

// ---------------- FC GEMV (fp32, weight-BW-bound) ----------------
__global__ __launch_bounds__(256)
void gemv_k(const float* __restrict__ Wm, const float* __restrict__ xv,
            float* __restrict__ y, int K)
{
    __shared__ float red[4];
    const int tid = threadIdx.x;
    const float4* row = (const float4*)(Wm + (size_t)blockIdx.x * K);
    const float4* x4  = (const float4*)xv;
    const int K4 = K >> 2;
    float sum = 0.f;
    for (int i = tid; i < K4; i += 256) {
        float4 a = row[i], b = x4[i];
        sum += a.x * b.x + a.y * b.y + a.z * b.z + a.w * b.w;
    }
#pragma unroll
    for (int off = 32; off > 0; off >>= 1) sum += __shfl_down(sum, off, 64);
    if ((tid & 63) == 0) red[tid >> 6] = sum;
    __syncthreads();
    if (tid == 0) y[blockIdx.x] = red[0] + red[1] + red[2] + red[3];
}

// ---------------- launcher ----------------
extern "C" void kernel_launch(void* const* d_in, const int* in_sizes, int n_in,
                              void* d_out, int out_size, void* d_ws, size_t ws_size,
                              hipStream_t stream)
{
    (void)in_sizes; (void)n_in; (void)out_size; (void)ws_size;
    const float* x = (const float*)d_in[0];
    const float* cw[13];
    for (int i = 0; i < 13; ++i) cw[i] = (const float*)d_in[5 + i];
    const float* fw1 = (const float*)d_in[18];
    const float* fw2 = (const float*)d_in[19];
    const float* fw3 = (const float*)d_in[20];
    float* outp = (float*)d_out;

    // layers 2..13 (index 0..11 here)
    static const int CIN[12]  = {64, 64, 128, 128, 256, 256, 256, 512, 512, 512, 512, 512};
    static const int COUT[12] = {64, 128, 128, 256, 256, 256, 512, 512, 512, 512, 512, 512};

    char* ws = (char*)d_ws;
    size_t wOff[12]; size_t o = 0;
    for (int i = 0; i < 12; ++i) { wOff[i] = o; o += (size_t)9 * COUT[i] * CIN[i]; }
    unsigned short* WT = (unsigned short*)ws;               // 29.4 MB bf16
    unsigned short* guardp = WT + o;                        // 256 B zero guard
    size_t ao = ((o + 128) * 2 + 255) & ~(size_t)255;
    unsigned short* bA = (unsigned short*)(ws + ao);        // 8.39 MB
    unsigned short* bB = (unsigned short*)(ws + ao + 8388608);
    float* fcIn = (float*)bA;                               // L13 result (128 KB)
    float* F1 = (float*)bB;
    float* F2 = F1 + 4096;

    // fused weight transform (also zeroes the halo guard)
    WtArgs wa; int blk = 0;
    {
        size_t oo = 0;
        for (int i = 0; i < 12; ++i) {
            wa.d[i].src = cw[i + 1];
            wa.d[i].dst = (unsigned)oo;
            wa.d[i].cin = CIN[i];
            wa.d[i].cout = COUT[i];
            wa.d[i].blk0 = blk;
            oo += (size_t)9 * COUT[i] * CIN[i];
            blk += COUT[i] / 4;
        }
    }
    wt_all_k<<<blk, 256, 0, stream>>>(wa, WT, guardp);

    // L1: fp32 vector conv 3->64 @256^2, out NHWC bf16
    conv1_k<<<dim3(16, 16, 2), 256, 0, stream>>>(x, cw[0], bA);

    // L2: 64->64 @256^2, fused pool -> bB @128^2
    conv_mfma_k<16, 32, 3><<<dim3(256, 2), 256, 0, stream>>>(bA, WT + wOff[0], guardp, bB, 64, 64, 256, 256);
    // L3: 64->128 @128^2 -> bA
    conv_mfma_k<8, 32, 0><<<dim3(128, 4), 256, 0, stream>>>(bB, WT + wOff[1], guardp, bA, 64, 128, 128, 128);
    // L4: 128->128 @128^2, fused pool -> bB @64^2
    conv_mfma_k<8, 32, 3><<<dim3(128, 4), 256, 0, stream>>>(bA, WT + wOff[2], guardp, bB, 128, 128, 128, 128);
    // L5: 128->256 @64^2 -> bA
    conv_mfma_k<8, 32, 0><<<dim3(32, 8), 256, 0, stream>>>(bB, WT + wOff[3], guardp, bA, 128, 256, 64, 64);
    // L6: 256->256 @64^2 -> bB
    conv_mfma_k<8, 32, 0><<<dim3(32, 8), 256, 0, stream>>>(bA, WT + wOff[4], guardp, bB, 256, 256, 64, 64);
    // L7: 256->256 @64^2, fused pool -> bA @32^2
    conv_mfma_k<8, 32, 3><<<dim3(32, 8), 256, 0, stream>>>(bB, WT + wOff[5], guardp, bA, 256, 256, 64, 64);
    // L8: 256->512 @32^2 -> bB
    conv_mfma_k<4, 32, 0><<<dim3(16, 16), 256, 0, stream>>>(bA, WT + wOff[6], guardp, bB, 256, 512, 32, 32);
    // L9: 512->512 @32^2 -> bA
    conv_mfma_k<4, 32, 0><<<dim3(16, 16), 256, 0, stream>>>(bB, WT + wOff[7], guardp, bA, 512, 512, 32, 32);
    // L10: 512->512 @32^2, fused pool -> bB @16^2
    conv_mfma_k<8, 32, 3><<<dim3(8, 16), 256, 0, stream>>>(bA, WT + wOff[8], guardp, bB, 512, 512, 32, 32);
    // L11: 512->512 @16^2 -> bA
    conv_mfma_k<4, 32, 0><<<dim3(4, 16), 256, 0, stream>>>(bB, WT + wOff[9], guardp, bA, 512, 512, 16, 16);
    // L12: 512->512 @16^2 -> bB
    conv_mfma_k<4, 32, 0><<<dim3(4, 16), 256, 0, stream>>>(bA, WT + wOff[10], guardp, bB, 512, 512, 16, 16);
    // L13: 512->512 @16^2, fused pool -> fp32 NCHW [512][8][8] (fcIn = bA)
    conv_mfma_k<8, 32, 4><<<dim3(2, 16), 256, 0, stream>>>(bB, WT + wOff[11], guardp, fcIn, 512, 512, 16, 16);

    // FC head (fp32, HBM-bound on weights)
    gemv_k<<<4096, 256, 0, stream>>>(fw1, fcIn, F1, 32768);
    gemv_k<<<4096, 256, 0, stream>>>(fw2, F1, F2, 4096);
    gemv_k<<<1000, 256, 0, stream>>>(fw3, F2, outp, 4096);
}